// Round 12
// baseline (177.438 us; speedup 1.0000x reference)
//
#include <hip/hip_runtime.h>
#include <hip/hip_bf16.h>

#define BN 8192
#define DIM 512
#define NB  64            // BN / 128 block-rows
#define NTILES 2080       // NB*(NB+1)/2 upper-triangle tiles
#define EPSF 1e-8f

using v8i   = __attribute__((ext_vector_type(8))) int;
using v4i   = __attribute__((ext_vector_type(4))) int;
using f32x4 = __attribute__((ext_vector_type(4))) float;

// One wave per row: L2-normalize, x4 pre-scale, fp8 e4m3; out[0] zeroed by
// block 0 (replaces a memset dispatch).
__global__ __launch_bounds__(256) void normalize_kernel(
        const float* __restrict__ emb, unsigned char* __restrict__ E,
        float* __restrict__ out) {
    if (blockIdx.x == 0 && threadIdx.x == 0) out[0] = 0.f;
    int lane = threadIdx.x & 63;
    int row  = blockIdx.x * 4 + (threadIdx.x >> 6);
    const float4* src = (const float4*)(emb + (size_t)row * DIM);
    float4 a = src[lane];
    float4 b = src[lane + 64];
    float ss = a.x*a.x + a.y*a.y + a.z*a.z + a.w*a.w
             + b.x*b.x + b.y*b.y + b.z*b.z + b.w*b.w;
    #pragma unroll
    for (int m = 1; m < 64; m <<= 1) ss += __shfl_xor(ss, m, 64);
    float s4 = 4.0f / fmaxf(sqrtf(ss), 1e-12f);
    int pa = __builtin_amdgcn_cvt_pk_fp8_f32(a.x*s4, a.y*s4, 0, false);
    pa     = __builtin_amdgcn_cvt_pk_fp8_f32(a.z*s4, a.w*s4, pa, true);
    int pb = __builtin_amdgcn_cvt_pk_fp8_f32(b.x*s4, b.y*s4, 0, false);
    pb     = __builtin_amdgcn_cvt_pk_fp8_f32(b.z*s4, b.w*s4, pb, true);
    unsigned char* rowp = E + (size_t)row * DIM;
    ((unsigned*)rowp)[lane]         = (unsigned)pa;
    ((unsigned*)(rowp + 256))[lane] = (unsigned)pb;
}

// Upper-triangle 128x128 tiles, 1D grid (2080), triangular decode.
// fp8 MX MFMA 16x16x128. NO LDS in the K-loop: BOTH A and B fragments load
// directly global->VGPR from the L2-resident E (4 MB; FETCH_SIZE 18 MB
// proves residency). Zero barriers / staging / swizzle in the K-loop -- the
// compiler is free to software-pipeline 64 loads against 64 MFMAs.
// LDS = epilogue reduction buffers only (~29.7 KB): rowBuf pre-reduced by a
// shfl_xor(8) so it is [2][128][9]f2, colBuf [2][128][5]f2.
__global__ __launch_bounds__(256) void gemm_epi_kernel(
        const unsigned char* __restrict__ E, const int* __restrict__ labels,
        float* __restrict__ P, float* __restrict__ N) {
    __shared__ float2 rowBuf[2 * 128 * 9];    // 18432 B
    __shared__ float2 colBuf[2 * 128 * 5];    // 10240 B
    __shared__ int labI[128];
    __shared__ int labJ[128];

    int t  = blockIdx.x;
    int bi = (int)(64.5f - sqrtf(64.5f * 64.5f - 2.0f * (float)t));
    while (64 * (bi + 1) - ((bi + 1) * bi) / 2 <= t) ++bi;
    while (64 * bi - (bi * (bi - 1)) / 2 > t) --bi;
    int bj = bi + (t - (64 * bi - (bi * (bi - 1)) / 2));
    const bool diag = (bi == bj);
    const int i0 = bi * 128;
    const int j0 = bj * 128;

    const int tid  = threadIdx.x;
    const int wave = tid >> 6;
    const int lane = tid & 63;
    const int quad = lane >> 4;
    const int lrow = lane & 15;
    const int i_w  = (wave >> 1) * 64;
    const int j_w  = (wave & 1) * 64;

    if (tid < 128)       labI[tid]       = labels[i0 + tid];
    else                 labJ[tid - 128] = labels[j0 + tid - 128];
    __syncthreads();     // labels visible to epilogue (K-loop has no barriers)

    f32x4 acc[4][4];
    #pragma unroll
    for (int a = 0; a < 4; ++a)
        #pragma unroll
        for (int b = 0; b < 4; ++b)
            acc[a][b] = (f32x4){0.f, 0.f, 0.f, 0.f};

    // Fragment base pointers: lane (lrow, quad) of each 16-row operand group
    // reads 32 consecutive k-bytes at quad*32; k advances 128 B = 8 v4i.
    const v4i* aptr[4];
    const v4i* bptr[4];
    #pragma unroll
    for (int tt = 0; tt < 4; ++tt) {
        aptr[tt] = (const v4i*)(E +
            (size_t)(i0 + i_w + tt * 16 + lrow) * DIM + quad * 32);
        bptr[tt] = (const v4i*)(E +
            (size_t)(j0 + j_w + tt * 16 + lrow) * DIM + quad * 32);
    }

    #pragma unroll
    for (int k = 0; k < 4; ++k) {
        v8i af[4], bf[4];
        #pragma unroll
        for (int tt = 0; tt < 4; ++tt) {
            ((v4i*)&af[tt])[0] = aptr[tt][k * 8];
            ((v4i*)&af[tt])[1] = aptr[tt][k * 8 + 1];
            ((v4i*)&bf[tt])[0] = bptr[tt][k * 8];
            ((v4i*)&bf[tt])[1] = bptr[tt][k * 8 + 1];
        }
        #pragma unroll
        for (int ti = 0; ti < 4; ++ti)
            #pragma unroll
            for (int tj = 0; tj < 4; ++tj)
                acc[ti][tj] = __builtin_amdgcn_mfma_scale_f32_16x16x128_f8f6f4(
                                  af[ti], bf[tj], acc[ti][tj],
                                  0, 0,                 // fp8 e4m3 / e4m3
                                  0, 0x7F7F7F7F,        // A scale = 1.0
                                  0, 0x7F7F7F7F);       // B scale = 1.0
    }

    // Epilogue. C/D: col = lane&15, row = quad*4 + reg. acc = 16*S.
    const int vR = wave & 1;     // two waves sharing an i-range differ in j_w
    const int vC = wave >> 1;
    float psC[4] = {0.f, 0.f, 0.f, 0.f};
    float nsC[4] = {0.f, 0.f, 0.f, 0.f};
    #pragma unroll
    for (int ti = 0; ti < 4; ++ti) {
        #pragma unroll
        for (int reg = 0; reg < 4; ++reg) {
            int irow = i_w + ti * 16 + quad * 4 + reg;
            int li   = labI[irow];
            int gi   = i0 + irow;
            float ps = 0.f, ns = 0.f;
            #pragma unroll
            for (int tj = 0; tj < 4; ++tj) {
                int jcol = j_w + tj * 16 + lrow;
                int lj   = labJ[jcol];
                int gj   = j0 + jcol;
                float w  = __expf(fmaf(acc[ti][tj][reg], 0.0625f, -1.0f));
                bool same = (li == lj);
                float wp = (same && (gi != gj)) ? w : 0.f;
                float wn = same ? 0.f : w;
                ps += wp;  ns += wn;
                psC[tj] += wp;  nsC[tj] += wn;
            }
            // pre-reduce the 16 lrow partials to 8 (shfl over bit 3)
            ps += __shfl_xor(ps, 8, 64);
            ns += __shfl_xor(ns, 8, 64);
            if ((lrow & 8) == 0)
                rowBuf[(size_t)(vR * 128 + irow) * 9 + lrow] = (float2){ps, ns};
        }
    }
    #pragma unroll
    for (int tj = 0; tj < 4; ++tj) {
        int jcol = j_w + tj * 16 + lrow;
        colBuf[(size_t)(vC * 128 + jcol) * 5 + quad] = (float2){psC[tj], nsC[tj]};
    }
    __syncthreads();

    if (tid < 128) {
        const float2* a = rowBuf + (size_t)tid * 9;
        const float2* b = rowBuf + (size_t)(128 + tid) * 9;
        float sp = 0.f, sn = 0.f;
        #pragma unroll
        for (int u = 0; u < 8; ++u) {
            sp += a[u].x + b[u].x;
            sn += a[u].y + b[u].y;
        }
        P[(size_t)bj * BN + i0 + tid] = sp;
        N[(size_t)bj * BN + i0 + tid] = sn;
    } else if (!diag) {
        int c2 = tid - 128;
        const float2* a = colBuf + (size_t)c2 * 5;
        const float2* b = colBuf + (size_t)(128 + c2) * 5;
        float sp = 0.f, sn = 0.f;
        #pragma unroll
        for (int u = 0; u < 4; ++u) {
            sp += a[u].x + b[u].x;
            sn += a[u].y + b[u].y;
        }
        P[(size_t)bi * BN + j0 + c2] = sp;
        N[(size_t)bi * BN + j0 + c2] = sn;
    }
}

// Fused tail: 32 blocks x 256. Per-block LDS histogram, per-row partial
// reduce + loss, one atomicAdd of the pre-scaled block sum into out[0].
__global__ __launch_bounds__(256) void reduce_finalize_kernel(
        const int* __restrict__ labels, const float* __restrict__ P,
        const float* __restrict__ N, float* __restrict__ out) {
    __shared__ int cnt[128];
    __shared__ float wsum[4];
    int tid = threadIdx.x;
    if (tid < 128) cnt[tid] = 0;
    __syncthreads();
    for (int i = tid; i < BN; i += 256) atomicAdd(&cnt[labels[i]], 1);
    __syncthreads();

    int i = blockIdx.x * 256 + tid;
    float p = 0.f, n = 0.f;
    #pragma unroll 8
    for (int c = 0; c < NB; ++c) {
        p += P[(size_t)c * BN + i];
        n += N[(size_t)c * BN + i];
    }
    int   cl = cnt[labels[i]];
    float pm = p / fmaxf((float)(cl - 1), 1.0f);
    float nm = n / fmaxf((float)(BN - cl), 1.0f);
    float v  = ((cl - 1 > 0) && (BN - cl > 0))
                   ? -logf(pm / (pm + nm + EPSF)) : 0.0f;
    v *= (1.0f / (float)BN);
    #pragma unroll
    for (int m = 1; m < 64; m <<= 1) v += __shfl_xor(v, m, 64);
    if ((tid & 63) == 0) wsum[tid >> 6] = v;
    __syncthreads();
    if (tid == 0)
        atomicAdd(out, wsum[0] + wsum[1] + wsum[2] + wsum[3]);
}

extern "C" void kernel_launch(void* const* d_in, const int* in_sizes, int n_in,
                              void* d_out, int out_size, void* d_ws, size_t ws_size,
                              hipStream_t stream) {
    const float* emb   = (const float*)d_in[0];
    const int* labels  = (const int*)d_in[1];
    float* out         = (float*)d_out;

    // ws layout: E (8 MB reserved; fp8 uses 4) | P (2 MB) | N (2 MB)
    unsigned char* E   = (unsigned char*)d_ws;
    float* P           = (float*)((char*)d_ws + (size_t)BN * DIM * 2);
    float* N           = P + (size_t)NB * BN;

    normalize_kernel<<<BN / 4, 256, 0, stream>>>(emb, E, out);
    gemm_epi_kernel<<<NTILES, 256, 0, stream>>>(E, labels, P, N);
    reduce_finalize_kernel<<<32, 256, 0, stream>>>(labels, P, N, out);
}